// Round 3
// baseline (2484.955 us; speedup 1.0000x reference)
//
#include <hip/hip_runtime.h>

typedef unsigned short u16;
typedef unsigned int u32;
typedef __attribute__((ext_vector_type(8))) short s8v;   // 8 bf16 (4 VGPRs) MFMA A/B frag
typedef __attribute__((ext_vector_type(4))) float f4v;   // MFMA C/D frag

#define EMB 1024
#define SEQ 2048
#define BATCH 2
#define HEADS 16
#define HDIM 64
#define HID 4096
#define MROWS 4096   /* BATCH*SEQ */

__device__ __forceinline__ float bf2f(u16 h) {
    u32 u = ((u32)h) << 16;
    union { u32 u; float f; } v; v.u = u; return v.f;
}
__device__ __forceinline__ u16 f2bf(float f) {
    union { float f; u32 u; } v; v.f = f;
    u32 r = v.u + 0x7FFFu + ((v.u >> 16) & 1u);   // RNE
    return (u16)(r >> 16);
}

__device__ __forceinline__ void gload16(const void* g, void* l) {
    __builtin_amdgcn_global_load_lds(
        (const __attribute__((address_space(1))) unsigned int*)g,
        (__attribute__((address_space(3))) unsigned int*)l, 16, 0, 0);
}

// ---------------- transpose + f32->bf16 cast:  WT[n][k] = bf16(W[k][n]) ----------------
__global__ __launch_bounds__(256) void transpose_cast(const float* __restrict__ W,
                                                      u16* __restrict__ WT, int K, int N) {
    __shared__ float tile[32][33];
    int n0 = blockIdx.x * 32, k0 = blockIdx.y * 32;
    int tx = threadIdx.x, ty = threadIdx.y;   // 32 x 8
#pragma unroll
    for (int i = ty; i < 32; i += 8)
        tile[i][tx] = W[(size_t)(k0 + i) * N + n0 + tx];
    __syncthreads();
#pragma unroll
    for (int i = ty; i < 32; i += 8)
        WT[(size_t)(n0 + i) * K + k0 + tx] = f2bf(tile[tx][i]);
}

// ---------------- layernorm f32 -> bf16 ----------------
__global__ __launch_bounds__(256) void ln_kernel(const float* __restrict__ in,
                                                 const float* __restrict__ w,
                                                 const float* __restrict__ b,
                                                 u16* __restrict__ out) {
    const int row = blockIdx.x, t = threadIdx.x;
    const float4* rp = (const float4*)(in + (size_t)row * EMB);
    float4 v = rp[t];
    float s = v.x + v.y + v.z + v.w;
    __shared__ float red[4];
#pragma unroll
    for (int off = 32; off; off >>= 1) s += __shfl_xor(s, off);
    if ((t & 63) == 0) red[t >> 6] = s;
    __syncthreads();
    float mean = (red[0] + red[1] + red[2] + red[3]) * (1.f / EMB);
    float dx = v.x - mean, dy = v.y - mean, dz = v.z - mean, dw = v.w - mean;
    float ss = dx * dx + dy * dy + dz * dz + dw * dw;
#pragma unroll
    for (int off = 32; off; off >>= 1) ss += __shfl_xor(ss, off);
    __syncthreads();
    if ((t & 63) == 0) red[t >> 6] = ss;
    __syncthreads();
    float var = (red[0] + red[1] + red[2] + red[3]) * (1.f / EMB);
    float rstd = rsqrtf(var + 1e-5f);
    float4 wv = ((const float4*)w)[t];
    float4 bv = ((const float4*)b)[t];
    u16* op = out + (size_t)row * EMB + t * 4;
    op[0] = f2bf(dx * rstd * wv.x + bv.x);
    op[1] = f2bf(dy * rstd * wv.y + bv.y);
    op[2] = f2bf(dz * rstd * wv.z + bv.z);
    op[3] = f2bf(dw * rstd * wv.w + bv.w);
}

// ---------------- bf16 MFMA GEMM: C[M,N] = A[M,K] @ BT[N,K]^T, m97 structure ----------------
// EPI: 0 = bf16 out; 1 = f32 out + bias + f32 residual (res MAY alias outp); 2 = bf16 out + bias + relu
template <int EPI>
__global__ __launch_bounds__(256) void gemm_bt(const u16* __restrict__ A, const u16* __restrict__ BT,
                                               const float* __restrict__ bias, const float* res,
                                               void* outp, int M, int N, int K) {
    __shared__ u16 As[128 * 32];
    __shared__ u16 Bs[128 * 32];
    const int t = threadIdx.x, w = t >> 6, lane = t & 63;
    const int m0 = blockIdx.y * 128, n0 = blockIdx.x * 128;
    const int wr = w >> 1, wc = w & 1;
    const int la = lane & 15, lb = lane >> 4;
    f4v acc[4][4] = {};

    const int srow = w * 16 + (lane >> 2);   // staging row within tile (0..63, +64 second call)
    const int scolb = (lane & 3) * 16;       // staging byte col within 64B row
    const char* Ab = (const char*)A;
    const char* Bb = (const char*)BT;
    const size_t strideb = (size_t)K * 2;
    char* AsB = (char*)As;
    char* BsB = (char*)Bs;

    for (int k0 = 0; k0 < K; k0 += 32) {
        __syncthreads();
        gload16(Ab + (size_t)(m0 + srow) * strideb + (size_t)k0 * 2 + scolb, AsB + w * 1024);
        gload16(Ab + (size_t)(m0 + srow + 64) * strideb + (size_t)k0 * 2 + scolb, AsB + 4096 + w * 1024);
        gload16(Bb + (size_t)(n0 + srow) * strideb + (size_t)k0 * 2 + scolb, BsB + w * 1024);
        gload16(Bb + (size_t)(n0 + srow + 64) * strideb + (size_t)k0 * 2 + scolb, BsB + 4096 + w * 1024);
        __syncthreads();

        s8v a[4], bf[4];
#pragma unroll
        for (int i = 0; i < 4; i++)
            a[i] = *(const s8v*)&As[(wr * 64 + i * 16 + la) * 32 + lb * 8];
#pragma unroll
        for (int i = 0; i < 4; i++)
            bf[i] = *(const s8v*)&Bs[(wc * 64 + i * 16 + la) * 32 + lb * 8];
#pragma unroll
        for (int mi = 0; mi < 4; mi++)
#pragma unroll
            for (int ni = 0; ni < 4; ni++)
                acc[mi][ni] = __builtin_amdgcn_mfma_f32_16x16x32_bf16(a[mi], bf[ni], acc[mi][ni], 0, 0, 0);
    }

    const int orow = m0 + wr * 64, ocol = n0 + wc * 64;
#pragma unroll
    for (int mi = 0; mi < 4; mi++)
#pragma unroll
        for (int ni = 0; ni < 4; ni++)
#pragma unroll
            for (int j = 0; j < 4; j++) {
                int r = orow + mi * 16 + lb * 4 + j;
                int c = ocol + ni * 16 + la;
                float v = acc[mi][ni][j];
                if (EPI == 0) {
                    ((u16*)outp)[(size_t)r * N + c] = f2bf(v);
                } else if (EPI == 1) {
                    ((float*)outp)[(size_t)r * N + c] = v + bias[c] + res[(size_t)r * N + c];
                } else {
                    v += bias[c];
                    ((u16*)outp)[(size_t)r * N + c] = f2bf(fmaxf(v, 0.f));
                }
            }
}

// ---------------- causal attention, 2 q-rows per wave, scores in LDS ----------------
// QKV: [MROWS][3072] bf16 (Q | K | V each 1024 wide). O: [MROWS][1024] bf16.
__global__ __launch_bounds__(256, 2) void attn_kernel(const u16* __restrict__ QKV, u16* __restrict__ O) {
    const int w = threadIdx.x >> 6, lane = threadIdx.x & 63;
    const int bh = blockIdx.y, b = bh >> 4, h = bh & 15;
    const int q0 = blockIdx.x * 8 + w * 2, q1 = q0 + 1;
    __shared__ float sc[8][SEQ];   // 64KB
    float* sc0 = sc[w * 2];
    float* sc1 = sc[w * 2 + 1];

    const u16* Qbase = QKV + (size_t)(b * SEQ) * 3072 + h * HDIM;
    const u16* Kbase = Qbase + 1024;
    const u16* Vbase = Qbase + 2048;

    // q rows into registers, pre-scaled
    float q0v[64], q1v[64];
    {
        const s8v* p0 = (const s8v*)(Qbase + (size_t)q0 * 3072);
        const s8v* p1 = (const s8v*)(Qbase + (size_t)q1 * 3072);
#pragma unroll
        for (int c = 0; c < 8; c++) {
            s8v t0 = p0[c], t1 = p1[c];
#pragma unroll
            for (int e = 0; e < 8; e++) {
                q0v[c * 8 + e] = bf2f((u16)t0[e]) * 0.125f;
                q1v[c * 8 + e] = bf2f((u16)t1[e]) * 0.125f;
            }
        }
    }

    // phase 1: scores
    float mx0 = -1e30f, mx1 = -1e30f;
    for (int k = lane; k <= q1; k += 64) {
        const s8v* kp = (const s8v*)(Kbase + (size_t)k * 3072);
        float s0 = 0.f, s1 = 0.f;
#pragma unroll
        for (int c = 0; c < 8; c++) {
            s8v tv = kp[c];
#pragma unroll
            for (int e = 0; e < 8; e++) {
                float f = bf2f((u16)tv[e]);
                s0 += q0v[c * 8 + e] * f;
                s1 += q1v[c * 8 + e] * f;
            }
        }
        sc1[k] = s1;
        mx1 = fmaxf(mx1, s1);
        if (k <= q0) { sc0[k] = s0; mx0 = fmaxf(mx0, s0); }
    }
#pragma unroll
    for (int off = 32; off; off >>= 1) {
        mx0 = fmaxf(mx0, __shfl_xor(mx0, off));
        mx1 = fmaxf(mx1, __shfl_xor(mx1, off));
    }

    // phase 1b: exp + sum
    float sm0 = 0.f, sm1 = 0.f;
    for (int k = lane; k <= q1; k += 64) {
        float p1 = __expf(sc1[k] - mx1); sc1[k] = p1; sm1 += p1;
        if (k <= q0) { float p0 = __expf(sc0[k] - mx0); sc0[k] = p0; sm0 += p0; }
    }
#pragma unroll
    for (int off = 32; off; off >>= 1) {
        sm0 += __shfl_xor(sm0, off);
        sm1 += __shfl_xor(sm1, off);
    }
    __syncthreads();   // make each wave's sc rows visible to all its lanes

    // phase 2: PV, lane = output dim
    const int d = lane;
    float a0 = 0.f, a1 = 0.f;
#pragma unroll 4
    for (int k = 0; k <= q0; k++) {
        float v = bf2f(Vbase[(size_t)k * 3072 + d]);
        a0 += sc0[k] * v;
        a1 += sc1[k] * v;
    }
    {
        float v = bf2f(Vbase[(size_t)q1 * 3072 + d]);
        a1 += sc1[q1] * v;
    }
    O[(size_t)(b * SEQ + q0) * EMB + h * HDIM + d] = f2bf(a0 / sm0);
    O[(size_t)(b * SEQ + q1) * EMB + h * HDIM + d] = f2bf(a1 / sm1);
}

extern "C" void kernel_launch(void* const* d_in, const int* in_sizes, int n_in,
                              void* d_out, int out_size, void* d_ws, size_t ws_size,
                              hipStream_t stream) {
    const float* x    = (const float*)d_in[0];
    const float* Wq   = (const float*)d_in[1];
    const float* Wk   = (const float*)d_in[2];
    const float* Wv   = (const float*)d_in[3];
    const float* Wo   = (const float*)d_in[4];
    const float* bo   = (const float*)d_in[5];
    const float* ln1w = (const float*)d_in[6];
    const float* ln1b = (const float*)d_in[7];
    const float* ln2w = (const float*)d_in[8];
    const float* ln2b = (const float*)d_in[9];
    const float* W1   = (const float*)d_in[10];
    const float* b1   = (const float*)d_in[11];
    const float* W2   = (const float*)d_in[12];
    const float* b2   = (const float*)d_in[13];

    // ---- workspace layout: exactly 64MB ----
    //  0..24MB : weights  (WqkvT 6 | WoT 2 | W1T 8 | W2T 8)
    // 24..32MB : xn  = LN1 out / attn out; REUSED as hn (LN2 out) after h-GEMM
    // 32..56MB : QKV (dead after attention)
    // 32..64MB : mid (REUSES QKV region + 8MB)
    const size_t MB = 1024 * 1024;
    char* ws = (char*)d_ws;
    u16* WqkvT = (u16*)(ws);              // [3072][1024] bf16 = 6MB
    u16* WoT   = (u16*)(ws + 6 * MB);     // [1024][1024] = 2MB
    u16* W1T   = (u16*)(ws + 8 * MB);     // [4096][1024] = 8MB
    u16* W2T   = (u16*)(ws + 16 * MB);    // [1024][4096] = 8MB
    u16* xn    = (u16*)(ws + 24 * MB);    // [4096][1024] = 8MB
    u16* QKV   = (u16*)(ws + 32 * MB);    // [4096][3072] = 24MB
    u16* mid   = (u16*)(ws + 32 * MB);    // [4096][4096] = 32MB (reuses QKV region)
    u16* hn    = xn;                      // LN2 out reuses xn region (xn dead after h-GEMM)
    float* hbuf = (float*)d_out;          // h lives in d_out (f32)

    dim3 tb(32, 8);
    transpose_cast<<<dim3(32, 32), tb, 0, stream>>>(Wq, WqkvT, 1024, 1024);
    transpose_cast<<<dim3(32, 32), tb, 0, stream>>>(Wk, WqkvT + (size_t)1024 * 1024, 1024, 1024);
    transpose_cast<<<dim3(32, 32), tb, 0, stream>>>(Wv, WqkvT + (size_t)2048 * 1024, 1024, 1024);
    transpose_cast<<<dim3(32, 32), tb, 0, stream>>>(Wo, WoT, 1024, 1024);
    transpose_cast<<<dim3(128, 32), tb, 0, stream>>>(W1, W1T, 1024, 4096);
    transpose_cast<<<dim3(32, 128), tb, 0, stream>>>(W2, W2T, 4096, 1024);

    ln_kernel<<<MROWS, 256, 0, stream>>>(x, ln1w, ln1b, xn);

    // QKV: [4096][3072]
    gemm_bt<0><<<dim3(3072 / 128, MROWS / 128), 256, 0, stream>>>(
        xn, WqkvT, nullptr, nullptr, QKV, MROWS, 3072, 1024);

    // attention -> xn (reuse; QKV fully consumed here)
    attn_kernel<<<dim3(SEQ / 8, BATCH * HEADS), 256, 0, stream>>>(QKV, xn);

    // h = x + attn @ Wo + bo  -> d_out (f32)
    gemm_bt<1><<<dim3(1024 / 128, MROWS / 128), 256, 0, stream>>>(
        xn, WoT, bo, x, hbuf, MROWS, 1024, 1024);

    // hn = LN2(h) (xn region is dead now)
    ln_kernel<<<MROWS, 256, 0, stream>>>(hbuf, ln2w, ln2b, hn);

    // mid = relu(hn @ W1 + b1)  (QKV region is dead now)
    gemm_bt<2><<<dim3(HID / 128, MROWS / 128), 256, 0, stream>>>(
        hn, W1T, b1, nullptr, mid, MROWS, HID, 1024);

    // out = h + mid @ W2 + b2  (in-place on d_out; same-thread per-element RAW)
    gemm_bt<1><<<dim3(1024 / 128, MROWS / 128), 256, 0, stream>>>(
        mid, W2T, b2, hbuf, hbuf, MROWS, 1024, HID);
}

// Round 4
// 379.442 us; speedup vs baseline: 6.5490x; 6.5490x over previous
//
#include <hip/hip_runtime.h>

typedef unsigned short u16;
typedef unsigned int u32;
typedef __attribute__((ext_vector_type(8))) short s8v;   // 8 bf16 (4 VGPRs) MFMA A/B frag
typedef __attribute__((ext_vector_type(4))) float f4v;   // MFMA C/D frag

#define EMB 1024
#define SEQ 2048
#define BATCH 2
#define HEADS 16
#define HDIM 64
#define HID 4096
#define MROWS 4096   /* BATCH*SEQ */

__device__ __forceinline__ float bf2f(u16 h) {
    u32 u = ((u32)h) << 16;
    union { u32 u; float f; } v; v.u = u; return v.f;
}
__device__ __forceinline__ u16 f2bf(float f) {
    union { float f; u32 u; } v; v.f = f;
    u32 r = v.u + 0x7FFFu + ((v.u >> 16) & 1u);   // RNE
    return (u16)(r >> 16);
}

__device__ __forceinline__ void gload16(const void* g, void* l) {
    __builtin_amdgcn_global_load_lds(
        (const __attribute__((address_space(1))) unsigned int*)g,
        (__attribute__((address_space(3))) unsigned int*)l, 16, 0, 0);
}

// ---------------- transpose + f32->bf16 cast:  WT[n][k] = bf16(W[k][n]) ----------------
__global__ __launch_bounds__(256) void transpose_cast(const float* __restrict__ W,
                                                      u16* __restrict__ WT, int K, int N) {
    __shared__ float tile[32][33];
    int n0 = blockIdx.x * 32, k0 = blockIdx.y * 32;
    int tx = threadIdx.x, ty = threadIdx.y;   // 32 x 8
#pragma unroll
    for (int i = ty; i < 32; i += 8)
        tile[i][tx] = W[(size_t)(k0 + i) * N + n0 + tx];
    __syncthreads();
#pragma unroll
    for (int i = ty; i < 32; i += 8)
        WT[(size_t)(n0 + i) * K + k0 + tx] = f2bf(tile[tx][i]);
}

// ---------------- layernorm f32 -> bf16 ----------------
__global__ __launch_bounds__(256) void ln_kernel(const float* __restrict__ in,
                                                 const float* __restrict__ w,
                                                 const float* __restrict__ b,
                                                 u16* __restrict__ out) {
    const int row = blockIdx.x, t = threadIdx.x;
    const float4* rp = (const float4*)(in + (size_t)row * EMB);
    float4 v = rp[t];
    float s = v.x + v.y + v.z + v.w;
    __shared__ float red[4];
#pragma unroll
    for (int off = 32; off; off >>= 1) s += __shfl_xor(s, off);
    if ((t & 63) == 0) red[t >> 6] = s;
    __syncthreads();
    float mean = (red[0] + red[1] + red[2] + red[3]) * (1.f / EMB);
    float dx = v.x - mean, dy = v.y - mean, dz = v.z - mean, dw = v.w - mean;
    float ss = dx * dx + dy * dy + dz * dz + dw * dw;
#pragma unroll
    for (int off = 32; off; off >>= 1) ss += __shfl_xor(ss, off);
    __syncthreads();
    if ((t & 63) == 0) red[t >> 6] = ss;
    __syncthreads();
    float var = (red[0] + red[1] + red[2] + red[3]) * (1.f / EMB);
    float rstd = rsqrtf(var + 1e-5f);
    float4 wv = ((const float4*)w)[t];
    float4 bv = ((const float4*)b)[t];
    u16* op = out + (size_t)row * EMB + t * 4;
    op[0] = f2bf(dx * rstd * wv.x + bv.x);
    op[1] = f2bf(dy * rstd * wv.y + bv.y);
    op[2] = f2bf(dz * rstd * wv.z + bv.z);
    op[3] = f2bf(dw * rstd * wv.w + bv.w);
}

// ---------------- bf16 MFMA GEMM: C[M,N] = A[M,K] @ BT[N,K]^T, m97 structure ----------------
// EPI: 0 = bf16 out; 1 = f32 out + bias + f32 residual (res MAY alias outp); 2 = bf16 out + bias + relu
template <int EPI>
__global__ __launch_bounds__(256) void gemm_bt(const u16* __restrict__ A, const u16* __restrict__ BT,
                                               const float* __restrict__ bias, const float* res,
                                               void* outp, int M, int N, int K) {
    __shared__ u16 As[128 * 32];
    __shared__ u16 Bs[128 * 32];
    const int t = threadIdx.x, w = t >> 6, lane = t & 63;
    const int m0 = blockIdx.y * 128, n0 = blockIdx.x * 128;
    const int wr = w >> 1, wc = w & 1;
    const int la = lane & 15, lb = lane >> 4;
    f4v acc[4][4] = {};

    const int srow = w * 16 + (lane >> 2);   // staging row within tile (0..63, +64 second call)
    const int scolb = (lane & 3) * 16;       // staging byte col within 64B row
    const char* Ab = (const char*)A;
    const char* Bb = (const char*)BT;
    const size_t strideb = (size_t)K * 2;
    char* AsB = (char*)As;
    char* BsB = (char*)Bs;

    for (int k0 = 0; k0 < K; k0 += 32) {
        __syncthreads();
        gload16(Ab + (size_t)(m0 + srow) * strideb + (size_t)k0 * 2 + scolb, AsB + w * 1024);
        gload16(Ab + (size_t)(m0 + srow + 64) * strideb + (size_t)k0 * 2 + scolb, AsB + 4096 + w * 1024);
        gload16(Bb + (size_t)(n0 + srow) * strideb + (size_t)k0 * 2 + scolb, BsB + w * 1024);
        gload16(Bb + (size_t)(n0 + srow + 64) * strideb + (size_t)k0 * 2 + scolb, BsB + 4096 + w * 1024);
        __syncthreads();

        s8v a[4], bf[4];
#pragma unroll
        for (int i = 0; i < 4; i++)
            a[i] = *(const s8v*)&As[(wr * 64 + i * 16 + la) * 32 + lb * 8];
#pragma unroll
        for (int i = 0; i < 4; i++)
            bf[i] = *(const s8v*)&Bs[(wc * 64 + i * 16 + la) * 32 + lb * 8];
#pragma unroll
        for (int mi = 0; mi < 4; mi++)
#pragma unroll
            for (int ni = 0; ni < 4; ni++)
                acc[mi][ni] = __builtin_amdgcn_mfma_f32_16x16x32_bf16(a[mi], bf[ni], acc[mi][ni], 0, 0, 0);
    }

    const int orow = m0 + wr * 64, ocol = n0 + wc * 64;
#pragma unroll
    for (int mi = 0; mi < 4; mi++)
#pragma unroll
        for (int ni = 0; ni < 4; ni++)
#pragma unroll
            for (int j = 0; j < 4; j++) {
                int r = orow + mi * 16 + lb * 4 + j;
                int c = ocol + ni * 16 + la;
                float v = acc[mi][ni][j];
                if (EPI == 0) {
                    ((u16*)outp)[(size_t)r * N + c] = f2bf(v);
                } else if (EPI == 1) {
                    ((float*)outp)[(size_t)r * N + c] = v + bias[c] + res[(size_t)r * N + c];
                } else {
                    v += bias[c];
                    ((u16*)outp)[(size_t)r * N + c] = f2bf(fmaxf(v, 0.f));
                }
            }
}

// ---------------- MFMA flash attention (causal) ----------------
// QKV: [MROWS][3072] bf16 (Q|K|V each 1024). O: [MROWS][1024] bf16.
// 1 block = (b,h) x 64 q-rows. 4 waves, each owns 16 q-rows. KV tiles of 64.
#define LDK 72   /* padded LDS row stride (bf16): +8 pad -> 2-way bank aliasing (free) */
__global__ __launch_bounds__(256) void fattn(const u16* __restrict__ QKV, u16* __restrict__ O) {
    const int t = threadIdx.x, w = t >> 6, lane = t & 63;
    const int la = lane & 15, lb = lane >> 4;
    // XCD-aware decode: each XCD gets 4 consecutive bh values (K+V = 2MB fits its L2)
    const u32 id = blockIdx.x;          // 0..1023
    const int bh = (int)((id & 7) * 4 + (id >> 8));
    const int qt = (int)((id >> 3) & 31);
    const int b = bh >> 4, h = bh & 15;
    const int qbase = qt * 64;

    __shared__ u16 K_lds[64 * LDK];
    __shared__ u16 Vt_lds[64 * LDK];
    __shared__ u16 P_lds[4][16 * LDK];

    const u16* base = QKV + (size_t)(b * SEQ) * 3072 + h * HDIM;
    const u16* Qg = base;
    const u16* Kg = base + 1024;
    const u16* Vg = base + 2048;

    // Q fragments (held in registers for the whole kernel): row = la, k(d) = dt*32 + lb*8
    s8v aq0, aq1;
    {
        const u16* qr = Qg + (size_t)(qbase + w * 16 + la) * 3072 + lb * 8;
        aq0 = *(const s8v*)(qr);
        aq1 = *(const s8v*)(qr + 32);
    }

    float m[4], l[4];
#pragma unroll
    for (int j = 0; j < 4; j++) { m[j] = -1e30f; l[j] = 0.f; }
    f4v oacc[4] = {};

    u16* pw = &P_lds[w][0];
    const int nkv = qt + 1;

    for (int kt = 0; kt < nkv; ++kt) {
        const int kv0 = kt * 64;
        const bool lastTile = (kt == qt);
        __syncthreads();   // protect K/V LDS reuse across iterations
        // ---- stage K tile [64][64] row-major into padded LDS ----
        {
            const int row = t >> 2, s = t & 3;
            const u16* kr = Kg + (size_t)(kv0 + row) * 3072;
            *(s8v*)&K_lds[row * LDK + s * 8] = *(const s8v*)(kr + s * 8);
            *(s8v*)&K_lds[row * LDK + (s + 4) * 8] = *(const s8v*)(kr + (s + 4) * 8);
        }
        // ---- stage V tile transposed: Vt[d][key] ----
        {
            const int ss = t >> 5, kp = t & 31;   // seg 0..7, key-pair 0..31
            const u16* v0 = Vg + (size_t)(kv0 + kp * 2) * 3072 + ss * 8;
            s8v va = *(const s8v*)(v0);
            s8v vb = *(const s8v*)(v0 + 3072);
            u32* vt32 = (u32*)Vt_lds;
#pragma unroll
            for (int j = 0; j < 8; j++)
                vt32[(ss * 8 + j) * (LDK / 2) + kp] =
                    (u32)(u16)va[j] | ((u32)(u16)vb[j] << 16);
        }
        __syncthreads();

        // ---- QK^T: sacc[kc] = 16q x 16k tile (kc-th group of 16 keys) ----
        f4v sacc[4] = {};
#pragma unroll
        for (int kc = 0; kc < 4; kc++) {
            s8v bk0 = *(const s8v*)&K_lds[(kc * 16 + la) * LDK + lb * 8];
            s8v bk1 = *(const s8v*)&K_lds[(kc * 16 + la) * LDK + 32 + lb * 8];
            sacc[kc] = __builtin_amdgcn_mfma_f32_16x16x32_bf16(aq0, bk0, sacc[kc], 0, 0, 0);
            sacc[kc] = __builtin_amdgcn_mfma_f32_16x16x32_bf16(aq1, bk1, sacc[kc], 0, 0, 0);
        }

        // ---- online softmax (rows lb*4+j are lane-local in C-layout) ----
#pragma unroll
        for (int j = 0; j < 4; j++) {
            const int qrow = w * 16 + lb * 4 + j;   // q within tile; absolute = qbase + qrow
            float s0 = sacc[0][j] * 0.125f;
            float s1 = sacc[1][j] * 0.125f;
            float s2 = sacc[2][j] * 0.125f;
            float s3 = sacc[3][j] * 0.125f;
            if (lastTile) {   // diagonal tile: mask k > q (k within tile = kc*16+la)
                if (0 * 16 + la > qrow) s0 = -1e30f;
                if (1 * 16 + la > qrow) s1 = -1e30f;
                if (2 * 16 + la > qrow) s2 = -1e30f;
                if (3 * 16 + la > qrow) s3 = -1e30f;
            }
            float mx = fmaxf(fmaxf(s0, s1), fmaxf(s2, s3));
            mx = fmaxf(mx, __shfl_xor(mx, 1));
            mx = fmaxf(mx, __shfl_xor(mx, 2));
            mx = fmaxf(mx, __shfl_xor(mx, 4));
            mx = fmaxf(mx, __shfl_xor(mx, 8));
            float mn = fmaxf(m[j], mx);
            float sc = __expf(m[j] - mn);
            m[j] = mn;
            float e0 = __expf(s0 - mn), e1 = __expf(s1 - mn);
            float e2 = __expf(s2 - mn), e3 = __expf(s3 - mn);
            float rs = (e0 + e1) + (e2 + e3);
            rs += __shfl_xor(rs, 1);
            rs += __shfl_xor(rs, 2);
            rs += __shfl_xor(rs, 4);
            rs += __shfl_xor(rs, 8);
            l[j] = l[j] * sc + rs;
#pragma unroll
            for (int dt = 0; dt < 4; dt++) oacc[dt][j] *= sc;
            // write P row (bf16) to per-wave LDS for A-frag relayout
            u16* pr = pw + (lb * 4 + j) * LDK + la;
            pr[0]  = f2bf(e0);
            pr[16] = f2bf(e1);
            pr[32] = f2bf(e2);
            pr[48] = f2bf(e3);
        }

        // ---- PV: O += P @ V (wave-local LDS; compiler inserts lgkm waits) ----
        s8v ap0 = *(const s8v*)&pw[la * LDK + lb * 8];
        s8v ap1 = *(const s8v*)&pw[la * LDK + 32 + lb * 8];
#pragma unroll
        for (int dt = 0; dt < 4; dt++) {
            s8v v0 = *(const s8v*)&Vt_lds[(dt * 16 + la) * LDK + lb * 8];
            s8v v1 = *(const s8v*)&Vt_lds[(dt * 16 + la) * LDK + 32 + lb * 8];
            oacc[dt] = __builtin_amdgcn_mfma_f32_16x16x32_bf16(ap0, v0, oacc[dt], 0, 0, 0);
            oacc[dt] = __builtin_amdgcn_mfma_f32_16x16x32_bf16(ap1, v1, oacc[dt], 0, 0, 0);
        }
    }

    // ---- epilogue: O[q][d] = oacc / l ----
#pragma unroll
    for (int dt = 0; dt < 4; dt++) {
#pragma unroll
        for (int j = 0; j < 4; j++) {
            const int q = qbase + w * 16 + lb * 4 + j;
            O[(size_t)(b * SEQ + q) * EMB + h * HDIM + dt * 16 + la] = f2bf(oacc[dt][j] / l[j]);
        }
    }
}

extern "C" void kernel_launch(void* const* d_in, const int* in_sizes, int n_in,
                              void* d_out, int out_size, void* d_ws, size_t ws_size,
                              hipStream_t stream) {
    const float* x    = (const float*)d_in[0];
    const float* Wq   = (const float*)d_in[1];
    const float* Wk   = (const float*)d_in[2];
    const float* Wv   = (const float*)d_in[3];
    const float* Wo   = (const float*)d_in[4];
    const float* bo   = (const float*)d_in[5];
    const float* ln1w = (const float*)d_in[6];
    const float* ln1b = (const float*)d_in[7];
    const float* ln2w = (const float*)d_in[8];
    const float* ln2b = (const float*)d_in[9];
    const float* W1   = (const float*)d_in[10];
    const float* b1   = (const float*)d_in[11];
    const float* W2   = (const float*)d_in[12];
    const float* b2   = (const float*)d_in[13];

    // ---- workspace layout: exactly 64MB ----
    const size_t MB = 1024 * 1024;
    char* ws = (char*)d_ws;
    u16* WqkvT = (u16*)(ws);              // [3072][1024] bf16 = 6MB
    u16* WoT   = (u16*)(ws + 6 * MB);     // [1024][1024] = 2MB
    u16* W1T   = (u16*)(ws + 8 * MB);     // [4096][1024] = 8MB
    u16* W2T   = (u16*)(ws + 16 * MB);    // [1024][4096] = 8MB
    u16* xn    = (u16*)(ws + 24 * MB);    // [4096][1024] = 8MB
    u16* QKV   = (u16*)(ws + 32 * MB);    // [4096][3072] = 24MB
    u16* mid   = (u16*)(ws + 32 * MB);    // [4096][4096] = 32MB (reuses QKV region)
    u16* hn    = xn;                      // LN2 out reuses xn (dead after h-GEMM)
    float* hbuf = (float*)d_out;          // h lives in d_out (f32)

    dim3 tb(32, 8);
    transpose_cast<<<dim3(32, 32), tb, 0, stream>>>(Wq, WqkvT, 1024, 1024);
    transpose_cast<<<dim3(32, 32), tb, 0, stream>>>(Wk, WqkvT + (size_t)1024 * 1024, 1024, 1024);
    transpose_cast<<<dim3(32, 32), tb, 0, stream>>>(Wv, WqkvT + (size_t)2048 * 1024, 1024, 1024);
    transpose_cast<<<dim3(32, 32), tb, 0, stream>>>(Wo, WoT, 1024, 1024);
    transpose_cast<<<dim3(128, 32), tb, 0, stream>>>(W1, W1T, 1024, 4096);
    transpose_cast<<<dim3(32, 128), tb, 0, stream>>>(W2, W2T, 4096, 1024);

    ln_kernel<<<MROWS, 256, 0, stream>>>(x, ln1w, ln1b, xn);

    // QKV: [4096][3072]
    gemm_bt<0><<<dim3(3072 / 128, MROWS / 128), 256, 0, stream>>>(
        xn, WqkvT, nullptr, nullptr, QKV, MROWS, 3072, 1024);

    // flash attention -> xn (reuse; QKV fully consumed here)
    fattn<<<dim3(1024), 256, 0, stream>>>(QKV, xn);

    // h = x + attn @ Wo + bo  -> d_out (f32)
    gemm_bt<1><<<dim3(1024 / 128, MROWS / 128), 256, 0, stream>>>(
        xn, WoT, bo, x, hbuf, MROWS, 1024, 1024);

    // hn = LN2(h) (xn region is dead now)
    ln_kernel<<<MROWS, 256, 0, stream>>>(hbuf, ln2w, ln2b, hn);

    // mid = relu(hn @ W1 + b1)  (QKV region is dead now)
    gemm_bt<2><<<dim3(HID / 128, MROWS / 128), 256, 0, stream>>>(
        hn, W1T, b1, nullptr, mid, MROWS, HID, 1024);

    // out = h + mid @ W2 + b2  (in-place on d_out; same-thread per-element RAW)
    gemm_bt<1><<<dim3(1024 / 128, MROWS / 128), 256, 0, stream>>>(
        mid, W2T, b2, hbuf, hbuf, MROWS, 1024, HID);
}

// Round 6
// 340.932 us; speedup vs baseline: 7.2887x; 1.1130x over previous
//
#include <hip/hip_runtime.h>

typedef unsigned short u16;
typedef unsigned int u32;
typedef __attribute__((ext_vector_type(8))) short s8v;   // 8 bf16 (4 VGPRs) MFMA A/B frag
typedef __attribute__((ext_vector_type(4))) float f4v;   // MFMA C/D frag

#define EMB 1024
#define SEQ 2048
#define BATCH 2
#define HEADS 16
#define HDIM 64
#define HID 4096
#define MROWS 4096   /* BATCH*SEQ */

__device__ __forceinline__ float bf2f(u16 h) {
    u32 u = ((u32)h) << 16;
    union { u32 u; float f; } v; v.u = u; return v.f;
}
__device__ __forceinline__ u16 f2bf(float f) {
    union { float f; u32 u; } v; v.f = f;
    u32 r = v.u + 0x7FFFu + ((v.u >> 16) & 1u);   // RNE
    return (u16)(r >> 16);
}

__device__ __forceinline__ void gload16(const void* g, void* l) {
    __builtin_amdgcn_global_load_lds(
        (const __attribute__((address_space(1))) unsigned int*)g,
        (__attribute__((address_space(3))) unsigned int*)l, 16, 0, 0);
}

// ---------------- transpose + f32->bf16 cast:  WT[n][k] = bf16(W[k][n]) ----------------
__global__ __launch_bounds__(256) void transpose_cast(const float* __restrict__ W,
                                                      u16* __restrict__ WT, int K, int N) {
    __shared__ float tile[32][33];
    int n0 = blockIdx.x * 32, k0 = blockIdx.y * 32;
    int tx = threadIdx.x, ty = threadIdx.y;   // 32 x 8
#pragma unroll
    for (int i = ty; i < 32; i += 8)
        tile[i][tx] = W[(size_t)(k0 + i) * N + n0 + tx];
    __syncthreads();
#pragma unroll
    for (int i = ty; i < 32; i += 8)
        WT[(size_t)(n0 + i) * K + k0 + tx] = f2bf(tile[tx][i]);
}

// ---------------- layernorm f32 -> bf16 ----------------
__global__ __launch_bounds__(256) void ln_kernel(const float* __restrict__ in,
                                                 const float* __restrict__ w,
                                                 const float* __restrict__ b,
                                                 u16* __restrict__ out) {
    const int row = blockIdx.x, t = threadIdx.x;
    const float4* rp = (const float4*)(in + (size_t)row * EMB);
    float4 v = rp[t];
    float s = v.x + v.y + v.z + v.w;
    __shared__ float red[4];
#pragma unroll
    for (int off = 32; off; off >>= 1) s += __shfl_xor(s, off);
    if ((t & 63) == 0) red[t >> 6] = s;
    __syncthreads();
    float mean = (red[0] + red[1] + red[2] + red[3]) * (1.f / EMB);
    float dx = v.x - mean, dy = v.y - mean, dz = v.z - mean, dw = v.w - mean;
    float ss = dx * dx + dy * dy + dz * dz + dw * dw;
#pragma unroll
    for (int off = 32; off; off >>= 1) ss += __shfl_xor(ss, off);
    __syncthreads();
    if ((t & 63) == 0) red[t >> 6] = ss;
    __syncthreads();
    float var = (red[0] + red[1] + red[2] + red[3]) * (1.f / EMB);
    float rstd = rsqrtf(var + 1e-5f);
    float4 wv = ((const float4*)w)[t];
    float4 bv = ((const float4*)b)[t];
    u16* op = out + (size_t)row * EMB + t * 4;
    op[0] = f2bf(dx * rstd * wv.x + bv.x);
    op[1] = f2bf(dy * rstd * wv.y + bv.y);
    op[2] = f2bf(dz * rstd * wv.z + bv.z);
    op[3] = f2bf(dw * rstd * wv.w + bv.w);
}

// ---------------- bf16 MFMA GEMM: C[M,N] = A[M,K] @ BT[N,K]^T, m97 structure ----------------
// EPI: 0 = bf16 out; 1 = f32 out + bias + f32 residual (res MAY alias outp); 2 = bf16 out + bias + relu
template <int EPI>
__global__ __launch_bounds__(256) void gemm_bt(const u16* __restrict__ A, const u16* __restrict__ BT,
                                               const float* __restrict__ bias, const float* res,
                                               void* outp, int M, int N, int K) {
    __shared__ u16 As[128 * 32];
    __shared__ u16 Bs[128 * 32];
    const int t = threadIdx.x, w = t >> 6, lane = t & 63;
    const int m0 = blockIdx.y * 128, n0 = blockIdx.x * 128;
    const int wr = w >> 1, wc = w & 1;
    const int la = lane & 15, lb = lane >> 4;
    f4v acc[4][4] = {};

    const int srow = w * 16 + (lane >> 2);   // staging row within tile (0..63, +64 second call)
    const int scolb = (lane & 3) * 16;       // staging byte col within 64B row
    const char* Ab = (const char*)A;
    const char* Bb = (const char*)BT;
    const size_t strideb = (size_t)K * 2;
    char* AsB = (char*)As;
    char* BsB = (char*)Bs;

    for (int k0 = 0; k0 < K; k0 += 32) {
        __syncthreads();
        gload16(Ab + (size_t)(m0 + srow) * strideb + (size_t)k0 * 2 + scolb, AsB + w * 1024);
        gload16(Ab + (size_t)(m0 + srow + 64) * strideb + (size_t)k0 * 2 + scolb, AsB + 4096 + w * 1024);
        gload16(Bb + (size_t)(n0 + srow) * strideb + (size_t)k0 * 2 + scolb, BsB + w * 1024);
        gload16(Bb + (size_t)(n0 + srow + 64) * strideb + (size_t)k0 * 2 + scolb, BsB + 4096 + w * 1024);
        __syncthreads();

        s8v a[4], bf[4];
#pragma unroll
        for (int i = 0; i < 4; i++)
            a[i] = *(const s8v*)&As[(wr * 64 + i * 16 + la) * 32 + lb * 8];
#pragma unroll
        for (int i = 0; i < 4; i++)
            bf[i] = *(const s8v*)&Bs[(wc * 64 + i * 16 + la) * 32 + lb * 8];
#pragma unroll
        for (int mi = 0; mi < 4; mi++)
#pragma unroll
            for (int ni = 0; ni < 4; ni++)
                acc[mi][ni] = __builtin_amdgcn_mfma_f32_16x16x32_bf16(a[mi], bf[ni], acc[mi][ni], 0, 0, 0);
    }

    const int orow = m0 + wr * 64, ocol = n0 + wc * 64;
#pragma unroll
    for (int mi = 0; mi < 4; mi++)
#pragma unroll
        for (int ni = 0; ni < 4; ni++)
#pragma unroll
            for (int j = 0; j < 4; j++) {
                int r = orow + mi * 16 + lb * 4 + j;
                int c = ocol + ni * 16 + la;
                float v = acc[mi][ni][j];
                if (EPI == 0) {
                    ((u16*)outp)[(size_t)r * N + c] = f2bf(v);
                } else if (EPI == 1) {
                    ((float*)outp)[(size_t)r * N + c] = v + bias[c] + res[(size_t)r * N + c];
                } else {
                    v += bias[c];
                    ((u16*)outp)[(size_t)r * N + c] = f2bf(fmaxf(v, 0.f));
                }
            }
}

// ---------------- MFMA flash attention (causal), balanced pair scheme ----------------
// QKV: [MROWS][3072] bf16 (Q|K|V each 1024). O: [MROWS][1024] bf16.
// 256 blocks x 512 threads. Block = (b,h) x q-tile PAIR (qt, 15-qt), q-tile = 128 rows.
// 8 waves, each owns 16 q-rows. KV tiles of 64 keys; every block does exactly 34 tile-steps.
#define LDK 72   /* padded LDS row stride (bf16) */
__global__ __launch_bounds__(512) void fattn(const u16* __restrict__ QKV, u16* __restrict__ O) {
    const int t = threadIdx.x, w = t >> 6, lane = t & 63;
    const int la = lane & 15, lb = lane >> 4;
    // decode: xcd = id&7; all 8 pair-blocks of a bh share an XCD (K+V 512KB/bh, 4 bh/XCD -> 2MB in L2)
    const u32 id = blockIdx.x;          // 0..255
    const int bh = (int)((id & 7) * 4 + ((id >> 6) & 3));
    const int p = (int)((id >> 3) & 7); // pair index 0..7
    const int b = bh >> 4, h = bh & 15;

    __shared__ u16 K_lds[64 * LDK];
    __shared__ u16 Vt_lds[64 * LDK];
    __shared__ u16 P_lds[8][16 * LDK];

    const u16* base = QKV + (size_t)(b * SEQ) * 3072 + h * HDIM;
    const u16* Qg = base;
    const u16* Kg = base + 1024;
    const u16* Vg = base + 2048;
    u16* pw = &P_lds[w][0];

    // staging work split: K by all 512 threads (1 x s8v), V-transpose by threads 0..255 (2 x s8v)
    const int krow = t >> 3, kseg = t & 7;
    const int vss = (t >> 5) & 7, vkp = t & 31;
    const bool vstager = (t < 256);

#pragma unroll
    for (int phase = 0; phase < 2; phase++) {
        const int qt = phase ? (15 - p) : p;
        const int qbase = qt * 128;
        const int nkv = 2 * qt + 2;
        const int wq0 = qbase + w * 16;   // wave's first absolute q row

        // Q fragments for this phase
        s8v aq0, aq1;
        {
            const u16* qr = Qg + (size_t)(wq0 + la) * 3072 + lb * 8;
            aq0 = *(const s8v*)(qr);
            aq1 = *(const s8v*)(qr + 32);
        }
        float m[4], l[4];
#pragma unroll
        for (int j = 0; j < 4; j++) { m[j] = -1e30f; l[j] = 0.f; }
        f4v oacc[4] = {};

        // prologue: prefetch tile 0 into registers
        s8v kstg, vstgA, vstgB;
        kstg = *(const s8v*)(Kg + (size_t)krow * 3072 + kseg * 8);
        if (vstager) {
            const u16* v0 = Vg + (size_t)(vkp * 2) * 3072 + vss * 8;
            vstgA = *(const s8v*)(v0);
            vstgB = *(const s8v*)(v0 + 3072);
        }

        for (int kt = 0; kt < nkv; ++kt) {
            const int kv0 = kt * 64;
            // write staged regs -> LDS (vmcnt wait auto-inserted on reg use)
            *(s8v*)&K_lds[krow * LDK + kseg * 8] = kstg;
            if (vstager) {
                u32* vt32 = (u32*)Vt_lds;
#pragma unroll
                for (int j2 = 0; j2 < 8; j2++)
                    vt32[(vss * 8 + j2) * (LDK / 2) + vkp] =
                        (u32)(u16)vstgA[j2] | ((u32)(u16)vstgB[j2] << 16);
            }
            // async prefetch of next tile (in flight across the compute phase)
            if (kt + 1 < nkv) {
                const int nv0 = kv0 + 64;
                kstg = *(const s8v*)(Kg + (size_t)(nv0 + krow) * 3072 + kseg * 8);
                if (vstager) {
                    const u16* v0 = Vg + (size_t)(nv0 + vkp * 2) * 3072 + vss * 8;
                    vstgA = *(const s8v*)(v0);
                    vstgB = *(const s8v*)(v0 + 3072);
                }
            }
            __syncthreads();

            if (kv0 <= wq0 + 15) {   // wave has at least one unmasked key in this tile
                // ---- QK^T ----
                f4v sacc[4] = {};
#pragma unroll
                for (int kc = 0; kc < 4; kc++) {
                    s8v bk0 = *(const s8v*)&K_lds[(kc * 16 + la) * LDK + lb * 8];
                    s8v bk1 = *(const s8v*)&K_lds[(kc * 16 + la) * LDK + 32 + lb * 8];
                    sacc[kc] = __builtin_amdgcn_mfma_f32_16x16x32_bf16(aq0, bk0, sacc[kc], 0, 0, 0);
                    sacc[kc] = __builtin_amdgcn_mfma_f32_16x16x32_bf16(aq1, bk1, sacc[kc], 0, 0, 0);
                }

                // ---- online softmax (rows lb*4+j lane-local) ----
                const bool doMask = (kv0 + 63 > wq0);
#pragma unroll
                for (int j = 0; j < 4; j++) {
                    const int row = wq0 + lb * 4 + j;
                    float s0 = sacc[0][j] * 0.125f;
                    float s1 = sacc[1][j] * 0.125f;
                    float s2 = sacc[2][j] * 0.125f;
                    float s3 = sacc[3][j] * 0.125f;
                    if (doMask) {
                        if (kv0 + 0 * 16 + la > row) s0 = -1e30f;
                        if (kv0 + 1 * 16 + la > row) s1 = -1e30f;
                        if (kv0 + 2 * 16 + la > row) s2 = -1e30f;
                        if (kv0 + 3 * 16 + la > row) s3 = -1e30f;
                    }
                    float mx = fmaxf(fmaxf(s0, s1), fmaxf(s2, s3));
                    mx = fmaxf(mx, __shfl_xor(mx, 1));
                    mx = fmaxf(mx, __shfl_xor(mx, 2));
                    mx = fmaxf(mx, __shfl_xor(mx, 4));
                    mx = fmaxf(mx, __shfl_xor(mx, 8));
                    float mn = fmaxf(m[j], mx);
                    float sc = __expf(m[j] - mn);
                    m[j] = mn;
                    float e0 = __expf(s0 - mn), e1 = __expf(s1 - mn);
                    float e2 = __expf(s2 - mn), e3 = __expf(s3 - mn);
                    float rs = (e0 + e1) + (e2 + e3);
                    rs += __shfl_xor(rs, 1);
                    rs += __shfl_xor(rs, 2);
                    rs += __shfl_xor(rs, 4);
                    rs += __shfl_xor(rs, 8);
                    l[j] = l[j] * sc + rs;
#pragma unroll
                    for (int dt = 0; dt < 4; dt++) oacc[dt][j] *= sc;
                    u16* pr = pw + (lb * 4 + j) * LDK + la;
                    pr[0]  = f2bf(e0);
                    pr[16] = f2bf(e1);
                    pr[32] = f2bf(e2);
                    pr[48] = f2bf(e3);
                }

                // ---- PV: O += P @ V ----
                s8v ap0 = *(const s8v*)&pw[la * LDK + lb * 8];
                s8v ap1 = *(const s8v*)&pw[la * LDK + 32 + lb * 8];
#pragma unroll
                for (int dt = 0; dt < 4; dt++) {
                    s8v v0 = *(const s8v*)&Vt_lds[(dt * 16 + la) * LDK + lb * 8];
                    s8v v1 = *(const s8v*)&Vt_lds[(dt * 16 + la) * LDK + 32 + lb * 8];
                    oacc[dt] = __builtin_amdgcn_mfma_f32_16x16x32_bf16(ap0, v0, oacc[dt], 0, 0, 0);
                    oacc[dt] = __builtin_amdgcn_mfma_f32_16x16x32_bf16(ap1, v1, oacc[dt], 0, 0, 0);
                }
            }
            __syncthreads();
        }

        // ---- epilogue for this phase ----
#pragma unroll
        for (int dt = 0; dt < 4; dt++) {
#pragma unroll
            for (int j = 0; j < 4; j++) {
                const int q = wq0 + lb * 4 + j;
                O[(size_t)(b * SEQ + q) * EMB + h * HDIM + dt * 16 + la] = f2bf(oacc[dt][j] / l[j]);
            }
        }
    }
}

extern "C" void kernel_launch(void* const* d_in, const int* in_sizes, int n_in,
                              void* d_out, int out_size, void* d_ws, size_t ws_size,
                              hipStream_t stream) {
    const float* x    = (const float*)d_in[0];
    const float* Wq   = (const float*)d_in[1];
    const float* Wk   = (const float*)d_in[2];
    const float* Wv   = (const float*)d_in[3];
    const float* Wo   = (const float*)d_in[4];
    const float* bo   = (const float*)d_in[5];
    const float* ln1w = (const float*)d_in[6];
    const float* ln1b = (const float*)d_in[7];
    const float* ln2w = (const float*)d_in[8];
    const float* ln2b = (const float*)d_in[9];
    const float* W1   = (const float*)d_in[10];
    const float* b1   = (const float*)d_in[11];
    const float* W2   = (const float*)d_in[12];
    const float* b2   = (const float*)d_in[13];

    // ---- workspace layout: exactly 64MB ----
    const size_t MB = 1024 * 1024;
    char* ws = (char*)d_ws;
    u16* WqkvT = (u16*)(ws);              // [3072][1024] bf16 = 6MB
    u16* WoT   = (u16*)(ws + 6 * MB);     // [1024][1024] = 2MB
    u16* W1T   = (u16*)(ws + 8 * MB);     // [4096][1024] = 8MB
    u16* W2T   = (u16*)(ws + 16 * MB);    // [1024][4096] = 8MB
    u16* xn    = (u16*)(ws + 24 * MB);    // [4096][1024] = 8MB
    u16* QKV   = (u16*)(ws + 32 * MB);    // [4096][3072] = 24MB
    u16* mid   = (u16*)(ws + 32 * MB);    // [4096][4096] = 32MB (reuses QKV region)
    u16* hn    = xn;                      // LN2 out reuses xn (dead after h-GEMM)
    float* hbuf = (float*)d_out;          // h lives in d_out (f32)

    dim3 tb(32, 8);
    transpose_cast<<<dim3(32, 32), tb, 0, stream>>>(Wq, WqkvT, 1024, 1024);
    transpose_cast<<<dim3(32, 32), tb, 0, stream>>>(Wk, WqkvT + (size_t)1024 * 1024, 1024, 1024);
    transpose_cast<<<dim3(32, 32), tb, 0, stream>>>(Wv, WqkvT + (size_t)2048 * 1024, 1024, 1024);
    transpose_cast<<<dim3(32, 32), tb, 0, stream>>>(Wo, WoT, 1024, 1024);
    transpose_cast<<<dim3(128, 32), tb, 0, stream>>>(W1, W1T, 1024, 4096);
    transpose_cast<<<dim3(32, 128), tb, 0, stream>>>(W2, W2T, 4096, 1024);

    ln_kernel<<<MROWS, 256, 0, stream>>>(x, ln1w, ln1b, xn);

    // QKV: [4096][3072]
    gemm_bt<0><<<dim3(3072 / 128, MROWS / 128), 256, 0, stream>>>(
        xn, WqkvT, nullptr, nullptr, QKV, MROWS, 3072, 1024);

    // flash attention -> xn (reuse; QKV fully consumed here)
    fattn<<<dim3(256), 512, 0, stream>>>(QKV, xn);

    // h = x + attn @ Wo + bo  -> d_out (f32)
    gemm_bt<1><<<dim3(1024 / 128, MROWS / 128), 256, 0, stream>>>(
        xn, WoT, bo, x, hbuf, MROWS, 1024, 1024);

    // hn = LN2(h) (xn region is dead now)
    ln_kernel<<<MROWS, 256, 0, stream>>>(hbuf, ln2w, ln2b, hn);

    // mid = relu(hn @ W1 + b1)  (QKV region is dead now)
    gemm_bt<2><<<dim3(HID / 128, MROWS / 128), 256, 0, stream>>>(
        hn, W1T, b1, nullptr, mid, MROWS, HID, 1024);

    // out = h + mid @ W2 + b2  (in-place on d_out; same-thread per-element RAW)
    gemm_bt<1><<<dim3(1024 / 128, MROWS / 128), 256, 0, stream>>>(
        mid, W2T, b2, hbuf, hbuf, MROWS, 1024, HID);
}

// Round 9
// 320.129 us; speedup vs baseline: 7.7624x; 1.0650x over previous
//
#include <hip/hip_runtime.h>

typedef unsigned short u16;
typedef unsigned int u32;
typedef __attribute__((ext_vector_type(8))) short s8v;   // 8 bf16 (4 VGPRs) MFMA A/B frag
typedef __attribute__((ext_vector_type(4))) float f4v;   // MFMA C/D frag

#define EMB 1024
#define SEQ 2048
#define BATCH 2
#define HEADS 16
#define HDIM 64
#define HID 4096
#define MROWS 4096   /* BATCH*SEQ */

__device__ __forceinline__ float bf2f(u16 h) {
    u32 u = ((u32)h) << 16;
    union { u32 u; float f; } v; v.u = u; return v.f;
}
__device__ __forceinline__ u16 f2bf(float f) {
    union { float f; u32 u; } v; v.f = f;
    u32 r = v.u + 0x7FFFu + ((v.u >> 16) & 1u);   // RNE
    return (u16)(r >> 16);
}

__device__ __forceinline__ void gload16(const void* g, void* l) {
    __builtin_amdgcn_global_load_lds(
        (const __attribute__((address_space(1))) unsigned int*)g,
        (__attribute__((address_space(3))) unsigned int*)l, 16, 0, 0);
}

// ---------------- transpose + f32->bf16 cast:  WT[n][k] = bf16(W[k][n]) ----------------
__global__ __launch_bounds__(256) void transpose_cast(const float* __restrict__ W,
                                                      u16* __restrict__ WT, int K, int N) {
    __shared__ float tile[32][33];
    int n0 = blockIdx.x * 32, k0 = blockIdx.y * 32;
    int tx = threadIdx.x, ty = threadIdx.y;   // 32 x 8
#pragma unroll
    for (int i = ty; i < 32; i += 8)
        tile[i][tx] = W[(size_t)(k0 + i) * N + n0 + tx];
    __syncthreads();
#pragma unroll
    for (int i = ty; i < 32; i += 8)
        WT[(size_t)(n0 + i) * K + k0 + tx] = f2bf(tile[tx][i]);
}

// ---------------- layernorm f32 -> bf16 ----------------
__global__ __launch_bounds__(256) void ln_kernel(const float* __restrict__ in,
                                                 const float* __restrict__ w,
                                                 const float* __restrict__ b,
                                                 u16* __restrict__ out) {
    const int row = blockIdx.x, t = threadIdx.x;
    const float4* rp = (const float4*)(in + (size_t)row * EMB);
    float4 v = rp[t];
    float s = v.x + v.y + v.z + v.w;
    __shared__ float red[4];
#pragma unroll
    for (int off = 32; off; off >>= 1) s += __shfl_xor(s, off);
    if ((t & 63) == 0) red[t >> 6] = s;
    __syncthreads();
    float mean = (red[0] + red[1] + red[2] + red[3]) * (1.f / EMB);
    float dx = v.x - mean, dy = v.y - mean, dz = v.z - mean, dw = v.w - mean;
    float ss = dx * dx + dy * dy + dz * dz + dw * dw;
#pragma unroll
    for (int off = 32; off; off >>= 1) ss += __shfl_xor(ss, off);
    __syncthreads();
    if ((t & 63) == 0) red[t >> 6] = ss;
    __syncthreads();
    float var = (red[0] + red[1] + red[2] + red[3]) * (1.f / EMB);
    float rstd = rsqrtf(var + 1e-5f);
    float4 wv = ((const float4*)w)[t];
    float4 bv = ((const float4*)b)[t];
    u16* op = out + (size_t)row * EMB + t * 4;
    op[0] = f2bf(dx * rstd * wv.x + bv.x);
    op[1] = f2bf(dy * rstd * wv.y + bv.y);
    op[2] = f2bf(dz * rstd * wv.z + bv.z);
    op[3] = f2bf(dw * rstd * wv.w + bv.w);
}

// ---------------- bf16 MFMA GEMM, double-buffered, XCD-swizzled ----------------
// C[M,N] = A[M,K] @ BT[N,K]^T.  1-D grid of nbx*32 blocks (M fixed = 4096 -> 32 row-panels).
// Decode: xcd=id&7 owns row-panels {xcd, xcd+8, xcd+16, xcd+24}; bx sweeps with the 4 panels inner,
// so each XCD keeps 4 A-panels + current B-tile in its L2.
// EPI: 0 = bf16 out; 1 = f32 out + bias + f32 residual (res MAY alias outp); 2 = bf16 out + bias + relu
template <int EPI>
__global__ __launch_bounds__(256) void gemm_bt(const u16* __restrict__ A, const u16* __restrict__ BT,
                                               const float* __restrict__ bias, const float* res,
                                               void* outp, int M, int N, int K) {
    __shared__ u16 As[2][128 * 32];
    __shared__ u16 Bs[2][128 * 32];
    const int t = threadIdx.x, w = t >> 6, lane = t & 63;
    const u32 id = blockIdx.x;
    const int xcd = (int)(id & 7), j = (int)(id >> 3);
    const int by = xcd + (j & 3) * 8;   // row-panel (nby == 32 always)
    const int bx = j >> 2;              // col-panel
    const int m0 = by * 128, n0 = bx * 128;
    const int wr = w >> 1, wc = w & 1;
    const int la = lane & 15, lb = lane >> 4;
    f4v acc[4][4] = {};

    const int srow = w * 16 + (lane >> 2);   // staging row within half-tile
    const int scolb = (lane & 3) * 16;       // staging byte col within 64B row
    const char* Ab = (const char*)A;
    const char* Bb = (const char*)BT;
    const size_t strideb = (size_t)K * 2;
    char* AsB = (char*)As;
    char* BsB = (char*)Bs;
    const size_t arow0 = (size_t)(m0 + srow) * strideb + scolb;
    const size_t arow1 = (size_t)(m0 + srow + 64) * strideb + scolb;
    const size_t brow0 = (size_t)(n0 + srow) * strideb + scolb;
    const size_t brow1 = (size_t)(n0 + srow + 64) * strideb + scolb;

    // prologue: stage tile 0 into buffer 0
    gload16(Ab + arow0, AsB + w * 1024);
    gload16(Ab + arow1, AsB + 4096 + w * 1024);
    gload16(Bb + brow0, BsB + w * 1024);
    gload16(Bb + brow1, BsB + 4096 + w * 1024);
    __syncthreads();   // compiler drains vmcnt before barrier

    int cur = 0;
    for (int k0 = 0; k0 < K; k0 += 32) {
        // issue next tile's loads into the other buffer (in flight across compute)
        if (k0 + 32 < K) {
            const size_t ko = (size_t)(k0 + 32) * 2;
            const int bo = (cur ^ 1) * 8192;
            gload16(Ab + arow0 + ko, AsB + bo + w * 1024);
            gload16(Ab + arow1 + ko, AsB + bo + 4096 + w * 1024);
            gload16(Bb + brow0 + ko, BsB + bo + w * 1024);
            gload16(Bb + brow1 + ko, BsB + bo + 4096 + w * 1024);
        }
        // compute on current buffer
        s8v a[4], bf[4];
#pragma unroll
        for (int i = 0; i < 4; i++)
            a[i] = *(const s8v*)&As[cur][(wr * 64 + i * 16 + la) * 32 + lb * 8];
#pragma unroll
        for (int i = 0; i < 4; i++)
            bf[i] = *(const s8v*)&Bs[cur][(wc * 64 + i * 16 + la) * 32 + lb * 8];
#pragma unroll
        for (int mi = 0; mi < 4; mi++)
#pragma unroll
            for (int ni = 0; ni < 4; ni++)
                acc[mi][ni] = __builtin_amdgcn_mfma_f32_16x16x32_bf16(a[mi], bf[ni], acc[mi][ni], 0, 0, 0);
        __syncthreads();   // vmcnt(0) drain here covers the prefetch; one barrier per K-step
        cur ^= 1;
    }

    const int orow = m0 + wr * 64, ocol = n0 + wc * 64;
#pragma unroll
    for (int mi = 0; mi < 4; mi++)
#pragma unroll
        for (int ni = 0; ni < 4; ni++)
#pragma unroll
            for (int j2 = 0; j2 < 4; j2++) {
                int r = orow + mi * 16 + lb * 4 + j2;
                int c = ocol + ni * 16 + la;
                float v = acc[mi][ni][j2];
                if (EPI == 0) {
                    ((u16*)outp)[(size_t)r * N + c] = f2bf(v);
                } else if (EPI == 1) {
                    ((float*)outp)[(size_t)r * N + c] = v + bias[c] + res[(size_t)r * N + c];
                } else {
                    v += bias[c];
                    ((u16*)outp)[(size_t)r * N + c] = f2bf(fmaxf(v, 0.f));
                }
            }
}

// ---------------- MFMA flash attention (causal), balanced pair scheme ----------------
// QKV: [MROWS][3072] bf16 (Q|K|V each 1024). O: [MROWS][1024] bf16.
// 256 blocks x 512 threads. Block = (b,h) x q-tile PAIR (qt, 15-qt), q-tile = 128 rows.
// 8 waves, each owns 16 q-rows. KV tiles of 64 keys; every block does exactly 34 tile-steps.
#define LDK 72   /* padded LDS row stride (bf16) */
__global__ __launch_bounds__(512) void fattn(const u16* __restrict__ QKV, u16* __restrict__ O) {
    const int t = threadIdx.x, w = t >> 6, lane = t & 63;
    const int la = lane & 15, lb = lane >> 4;
    // decode: xcd = id&7; all 8 pair-blocks of a bh share an XCD (K+V 512KB/bh, 4 bh/XCD -> 2MB in L2)
    const u32 id = blockIdx.x;          // 0..255
    const int bh = (int)((id & 7) * 4 + ((id >> 6) & 3));
    const int p = (int)((id >> 3) & 7); // pair index 0..7
    const int b = bh >> 4, h = bh & 15;

    __shared__ u16 K_lds[64 * LDK];
    __shared__ u16 Vt_lds[64 * LDK];
    __shared__ u16 P_lds[8][16 * LDK];

    const u16* base = QKV + (size_t)(b * SEQ) * 3072 + h * HDIM;
    const u16* Qg = base;
    const u16* Kg = base + 1024;
    const u16* Vg = base + 2048;
    u16* pw = &P_lds[w][0];

    // staging work split: K by all 512 threads (1 x s8v), V-transpose by threads 0..255 (2 x s8v)
    const int krow = t >> 3, kseg = t & 7;
    const int vss = (t >> 5) & 7, vkp = t & 31;
    const bool vstager = (t < 256);

#pragma unroll
    for (int phase = 0; phase < 2; phase++) {
        const int qt = phase ? (15 - p) : p;
        const int qbase = qt * 128;
        const int nkv = 2 * qt + 2;
        const int wq0 = qbase + w * 16;   // wave's first absolute q row

        // Q fragments for this phase
        s8v aq0, aq1;
        {
            const u16* qr = Qg + (size_t)(wq0 + la) * 3072 + lb * 8;
            aq0 = *(const s8v*)(qr);
            aq1 = *(const s8v*)(qr + 32);
        }
        float m[4], l[4];
#pragma unroll
        for (int j = 0; j < 4; j++) { m[j] = -1e30f; l[j] = 0.f; }
        f4v oacc[4] = {};

        // prologue: prefetch tile 0 into registers
        s8v kstg, vstgA, vstgB;
        kstg = *(const s8v*)(Kg + (size_t)krow * 3072 + kseg * 8);
        if (vstager) {
            const u16* v0 = Vg + (size_t)(vkp * 2) * 3072 + vss * 8;
            vstgA = *(const s8v*)(v0);
            vstgB = *(const s8v*)(v0 + 3072);
        }

        for (int kt = 0; kt < nkv; ++kt) {
            const int kv0 = kt * 64;
            // write staged regs -> LDS (vmcnt wait auto-inserted on reg use)
            *(s8v*)&K_lds[krow * LDK + kseg * 8] = kstg;
            if (vstager) {
                u32* vt32 = (u32*)Vt_lds;
#pragma unroll
                for (int j2 = 0; j2 < 8; j2++)
                    vt32[(vss * 8 + j2) * (LDK / 2) + vkp] =
                        (u32)(u16)vstgA[j2] | ((u32)(u16)vstgB[j2] << 16);
            }
            // async prefetch of next tile (in flight across the compute phase)
            if (kt + 1 < nkv) {
                const int nv0 = kv0 + 64;
                kstg = *(const s8v*)(Kg + (size_t)(nv0 + krow) * 3072 + kseg * 8);
                if (vstager) {
                    const u16* v0 = Vg + (size_t)(nv0 + vkp * 2) * 3072 + vss * 8;
                    vstgA = *(const s8v*)(v0);
                    vstgB = *(const s8v*)(v0 + 3072);
                }
            }
            __syncthreads();

            if (kv0 <= wq0 + 15) {   // wave has at least one unmasked key in this tile
                // ---- QK^T ----
                f4v sacc[4] = {};
#pragma unroll
                for (int kc = 0; kc < 4; kc++) {
                    s8v bk0 = *(const s8v*)&K_lds[(kc * 16 + la) * LDK + lb * 8];
                    s8v bk1 = *(const s8v*)&K_lds[(kc * 16 + la) * LDK + 32 + lb * 8];
                    sacc[kc] = __builtin_amdgcn_mfma_f32_16x16x32_bf16(aq0, bk0, sacc[kc], 0, 0, 0);
                    sacc[kc] = __builtin_amdgcn_mfma_f32_16x16x32_bf16(aq1, bk1, sacc[kc], 0, 0, 0);
                }

                // ---- online softmax (rows lb*4+j lane-local) ----
                const bool doMask = (kv0 + 63 > wq0);
#pragma unroll
                for (int j = 0; j < 4; j++) {
                    const int row = wq0 + lb * 4 + j;
                    float s0 = sacc[0][j] * 0.125f;
                    float s1 = sacc[1][j] * 0.125f;
                    float s2 = sacc[2][j] * 0.125f;
                    float s3 = sacc[3][j] * 0.125f;
                    if (doMask) {
                        if (kv0 + 0 * 16 + la > row) s0 = -1e30f;
                        if (kv0 + 1 * 16 + la > row) s1 = -1e30f;
                        if (kv0 + 2 * 16 + la > row) s2 = -1e30f;
                        if (kv0 + 3 * 16 + la > row) s3 = -1e30f;
                    }
                    float mx = fmaxf(fmaxf(s0, s1), fmaxf(s2, s3));
                    mx = fmaxf(mx, __shfl_xor(mx, 1));
                    mx = fmaxf(mx, __shfl_xor(mx, 2));
                    mx = fmaxf(mx, __shfl_xor(mx, 4));
                    mx = fmaxf(mx, __shfl_xor(mx, 8));
                    float mn = fmaxf(m[j], mx);
                    float sc = __expf(m[j] - mn);
                    m[j] = mn;
                    float e0 = __expf(s0 - mn), e1 = __expf(s1 - mn);
                    float e2 = __expf(s2 - mn), e3 = __expf(s3 - mn);
                    float rs = (e0 + e1) + (e2 + e3);
                    rs += __shfl_xor(rs, 1);
                    rs += __shfl_xor(rs, 2);
                    rs += __shfl_xor(rs, 4);
                    rs += __shfl_xor(rs, 8);
                    l[j] = l[j] * sc + rs;
#pragma unroll
                    for (int dt = 0; dt < 4; dt++) oacc[dt][j] *= sc;
                    u16* pr = pw + (lb * 4 + j) * LDK + la;
                    pr[0]  = f2bf(e0);
                    pr[16] = f2bf(e1);
                    pr[32] = f2bf(e2);
                    pr[48] = f2bf(e3);
                }

                // ---- PV: O += P @ V ----
                s8v ap0 = *(const s8v*)&pw[la * LDK + lb * 8];
                s8v ap1 = *(const s8v*)&pw[la * LDK + 32 + lb * 8];
#pragma unroll
                for (int dt = 0; dt < 4; dt++) {
                    s8v v0 = *(const s8v*)&Vt_lds[(dt * 16 + la) * LDK + lb * 8];
                    s8v v1 = *(const s8v*)&Vt_lds[(dt * 16 + la) * LDK + 32 + lb * 8];
                    oacc[dt] = __builtin_amdgcn_mfma_f32_16x16x32_bf16(ap0, v0, oacc[dt], 0, 0, 0);
                    oacc[dt] = __builtin_amdgcn_mfma_f32_16x16x32_bf16(ap1, v1, oacc[dt], 0, 0, 0);
                }
            }
            __syncthreads();
        }

        // ---- epilogue for this phase ----
#pragma unroll
        for (int dt = 0; dt < 4; dt++) {
#pragma unroll
            for (int j = 0; j < 4; j++) {
                const int q = wq0 + lb * 4 + j;
                O[(size_t)(b * SEQ + q) * EMB + h * HDIM + dt * 16 + la] = f2bf(oacc[dt][j] / l[j]);
            }
        }
    }
}

extern "C" void kernel_launch(void* const* d_in, const int* in_sizes, int n_in,
                              void* d_out, int out_size, void* d_ws, size_t ws_size,
                              hipStream_t stream) {
    const float* x    = (const float*)d_in[0];
    const float* Wq   = (const float*)d_in[1];
    const float* Wk   = (const float*)d_in[2];
    const float* Wv   = (const float*)d_in[3];
    const float* Wo   = (const float*)d_in[4];
    const float* bo   = (const float*)d_in[5];
    const float* ln1w = (const float*)d_in[6];
    const float* ln1b = (const float*)d_in[7];
    const float* ln2w = (const float*)d_in[8];
    const float* ln2b = (const float*)d_in[9];
    const float* W1   = (const float*)d_in[10];
    const float* b1   = (const float*)d_in[11];
    const float* W2   = (const float*)d_in[12];
    const float* b2   = (const float*)d_in[13];

    // ---- workspace layout: exactly 64MB ----
    const size_t MB = 1024 * 1024;
    char* ws = (char*)d_ws;
    u16* WqkvT = (u16*)(ws);              // [3072][1024] bf16 = 6MB
    u16* WoT   = (u16*)(ws + 6 * MB);     // [1024][1024] = 2MB
    u16* W1T   = (u16*)(ws + 8 * MB);     // [4096][1024] = 8MB
    u16* W2T   = (u16*)(ws + 16 * MB);    // [1024][4096] = 8MB
    u16* xn    = (u16*)(ws + 24 * MB);    // [4096][1024] = 8MB
    u16* QKV   = (u16*)(ws + 32 * MB);    // [4096][3072] = 24MB
    u16* mid   = (u16*)(ws + 32 * MB);    // [4096][4096] = 32MB (reuses QKV region)
    u16* hn    = xn;                      // LN2 out reuses xn (dead after h-GEMM)
    float* hbuf = (float*)d_out;          // h lives in d_out (f32)

    dim3 tb(32, 8);
    transpose_cast<<<dim3(32, 32), tb, 0, stream>>>(Wq, WqkvT, 1024, 1024);
    transpose_cast<<<dim3(32, 32), tb, 0, stream>>>(Wk, WqkvT + (size_t)1024 * 1024, 1024, 1024);
    transpose_cast<<<dim3(32, 32), tb, 0, stream>>>(Wv, WqkvT + (size_t)2048 * 1024, 1024, 1024);
    transpose_cast<<<dim3(32, 32), tb, 0, stream>>>(Wo, WoT, 1024, 1024);
    transpose_cast<<<dim3(128, 32), tb, 0, stream>>>(W1, W1T, 1024, 4096);
    transpose_cast<<<dim3(32, 128), tb, 0, stream>>>(W2, W2T, 4096, 1024);

    ln_kernel<<<MROWS, 256, 0, stream>>>(x, ln1w, ln1b, xn);

    // QKV: [4096][3072]   (1-D swizzled grid: nbx*32 blocks)
    gemm_bt<0><<<dim3((3072 / 128) * 32), 256, 0, stream>>>(
        xn, WqkvT, nullptr, nullptr, QKV, MROWS, 3072, 1024);

    // flash attention -> xn (reuse; QKV fully consumed here)
    fattn<<<dim3(256), 512, 0, stream>>>(QKV, xn);

    // h = x + attn @ Wo + bo  -> d_out (f32)
    gemm_bt<1><<<dim3((1024 / 128) * 32), 256, 0, stream>>>(
        xn, WoT, bo, x, hbuf, MROWS, 1024, 1024);

    // hn = LN2(h) (xn region is dead now)
    ln_kernel<<<MROWS, 256, 0, stream>>>(hbuf, ln2w, ln2b, hn);

    // mid = relu(hn @ W1 + b1)  (QKV region is dead now)
    gemm_bt<2><<<dim3((HID / 128) * 32), 256, 0, stream>>>(
        hn, W1T, b1, nullptr, mid, MROWS, HID, 1024);

    // out = h + mid @ W2 + b2  (in-place on d_out; same-thread per-element RAW)
    gemm_bt<1><<<dim3((1024 / 128) * 32), 256, 0, stream>>>(
        mid, W2T, b2, hbuf, hbuf, MROWS, 1024, HID);
}

// Round 10
// 295.366 us; speedup vs baseline: 8.4131x; 1.0838x over previous
//
#include <hip/hip_runtime.h>

typedef unsigned short u16;
typedef unsigned int u32;
typedef __attribute__((ext_vector_type(8))) short s8v;   // 8 bf16 (4 VGPRs) MFMA A/B frag
typedef __attribute__((ext_vector_type(4))) float f4v;   // MFMA C/D frag

#define EMB 1024
#define SEQ 2048
#define BATCH 2
#define HEADS 16
#define HDIM 64
#define HID 4096
#define MROWS 4096   /* BATCH*SEQ */

__device__ __forceinline__ float bf2f(u16 h) {
    u32 u = ((u32)h) << 16;
    union { u32 u; float f; } v; v.u = u; return v.f;
}
__device__ __forceinline__ u16 f2bf(float f) {
    union { float f; u32 u; } v; v.f = f;
    u32 r = v.u + 0x7FFFu + ((v.u >> 16) & 1u);   // RNE
    return (u16)(r >> 16);
}

__device__ __forceinline__ void gload16(const void* g, void* l) {
    __builtin_amdgcn_global_load_lds(
        (const __attribute__((address_space(1))) unsigned int*)g,
        (__attribute__((address_space(3))) unsigned int*)l, 16, 0, 0);
}

// ---------------- transpose + f32->bf16 cast:  WT[n][k] = bf16(W[k][n]) ----------------
__global__ __launch_bounds__(256) void transpose_cast(const float* __restrict__ W,
                                                      u16* __restrict__ WT, int K, int N) {
    __shared__ float tile[32][33];
    int n0 = blockIdx.x * 32, k0 = blockIdx.y * 32;
    int tx = threadIdx.x, ty = threadIdx.y;   // 32 x 8
#pragma unroll
    for (int i = ty; i < 32; i += 8)
        tile[i][tx] = W[(size_t)(k0 + i) * N + n0 + tx];
    __syncthreads();
#pragma unroll
    for (int i = ty; i < 32; i += 8)
        WT[(size_t)(n0 + i) * K + k0 + tx] = f2bf(tile[tx][i]);
}

// ---------------- layernorm f32 -> bf16 ----------------
__global__ __launch_bounds__(256) void ln_kernel(const float* __restrict__ in,
                                                 const float* __restrict__ w,
                                                 const float* __restrict__ b,
                                                 u16* __restrict__ out) {
    const int row = blockIdx.x, t = threadIdx.x;
    const float4* rp = (const float4*)(in + (size_t)row * EMB);
    float4 v = rp[t];
    float s = v.x + v.y + v.z + v.w;
    __shared__ float red[4];
#pragma unroll
    for (int off = 32; off; off >>= 1) s += __shfl_xor(s, off);
    if ((t & 63) == 0) red[t >> 6] = s;
    __syncthreads();
    float mean = (red[0] + red[1] + red[2] + red[3]) * (1.f / EMB);
    float dx = v.x - mean, dy = v.y - mean, dz = v.z - mean, dw = v.w - mean;
    float ss = dx * dx + dy * dy + dz * dz + dw * dw;
#pragma unroll
    for (int off = 32; off; off >>= 1) ss += __shfl_xor(ss, off);
    __syncthreads();
    if ((t & 63) == 0) red[t >> 6] = ss;
    __syncthreads();
    float var = (red[0] + red[1] + red[2] + red[3]) * (1.f / EMB);
    float rstd = rsqrtf(var + 1e-5f);
    float4 wv = ((const float4*)w)[t];
    float4 bv = ((const float4*)b)[t];
    u16* op = out + (size_t)row * EMB + t * 4;
    op[0] = f2bf(dx * rstd * wv.x + bv.x);
    op[1] = f2bf(dy * rstd * wv.y + bv.y);
    op[2] = f2bf(dz * rstd * wv.z + bv.z);
    op[3] = f2bf(dw * rstd * wv.w + bv.w);
}

// ---------------- bf16 MFMA GEMM, 64xTN tiles, double-buffered, XCD-swizzled ----------------
// C[M,N] = A[M,K] @ BT[N,K]^T.  M == 4096 -> 64 row-panels of 64.  Grid = (N/TN)*64 blocks.
// Decode: xcd=id&7 owns row-panels {xcd, xcd+8, ..., xcd+56}; panels inner, col-tiles outer.
// 4 waves in 2x2; each wave computes 32 x (TN/2).
// EPI: 0 = bf16 out; 1 = f32 out + bias + f32 residual (res MAY alias outp); 2 = bf16 out + bias + relu
template <int EPI, int TN>
__global__ __launch_bounds__(256) void gemm_bt(const u16* __restrict__ A, const u16* __restrict__ BT,
                                               const float* __restrict__ bias, const float* res,
                                               void* outp, int M, int N, int K) {
    constexpr int NB = TN / 32;            // b-frags per wave (2 or 4)
    constexpr int BBUF = TN * 64;          // B buffer bytes per stage (TN rows x 64B)
    __shared__ u16 As[2][64 * 32];         // 4KB per buffer
    __shared__ u16 Bs[2][TN * 32];         // 4 or 8KB per buffer
    const int t = threadIdx.x, w = t >> 6, lane = t & 63;
    const u32 id = blockIdx.x;
    const int xcd = (int)(id & 7), rem = (int)(id >> 3);
    const int by = xcd + (rem & 7) * 8;    // row-panel 0..63
    const int bx = rem >> 3;               // col-tile
    const int m0 = by * 64, n0 = bx * TN;
    const int wr = w >> 1, wc = w & 1;
    const int la = lane & 15, lb = lane >> 4;
    f4v acc[2][NB] = {};

    const int srow = t >> 2, sseg = t & 3;   // staging: row 0..63, 16B-seg 0..3
    const char* Ab = (const char*)A;
    const char* Bb = (const char*)BT;
    const size_t strideb = (size_t)K * 2;
    char* AsB = (char*)As;
    char* BsB = (char*)Bs;
    const size_t aoff  = (size_t)(m0 + srow) * strideb + sseg * 16;
    const size_t boff0 = (size_t)(n0 + srow) * strideb + sseg * 16;
    const size_t boff1 = (size_t)(n0 + srow + 64) * strideb + sseg * 16;  // TN==128 only

    // prologue: stage tile 0 into buffer 0
    gload16(Ab + aoff, AsB + w * 1024);
    gload16(Bb + boff0, BsB + w * 1024);
    if (TN == 128) gload16(Bb + boff1, BsB + 4096 + w * 1024);
    __syncthreads();

    int cur = 0;
    for (int k0 = 0; k0 < K; k0 += 32) {
        if (k0 + 32 < K) {   // prefetch next K-step into other buffer
            const size_t ko = (size_t)(k0 + 32) * 2;
            gload16(Ab + aoff + ko, AsB + (cur ^ 1) * 4096 + w * 1024);
            gload16(Bb + boff0 + ko, BsB + (cur ^ 1) * BBUF + w * 1024);
            if (TN == 128) gload16(Bb + boff1 + ko, BsB + (cur ^ 1) * BBUF + 4096 + w * 1024);
        }
        s8v a[2], bfr[NB];
#pragma unroll
        for (int i = 0; i < 2; i++)
            a[i] = *(const s8v*)&As[cur][(wr * 32 + i * 16 + la) * 32 + lb * 8];
#pragma unroll
        for (int i = 0; i < NB; i++)
            bfr[i] = *(const s8v*)&Bs[cur][(wc * (TN / 2) + i * 16 + la) * 32 + lb * 8];
#pragma unroll
        for (int mi = 0; mi < 2; mi++)
#pragma unroll
            for (int ni = 0; ni < NB; ni++)
                acc[mi][ni] = __builtin_amdgcn_mfma_f32_16x16x32_bf16(a[mi], bfr[ni], acc[mi][ni], 0, 0, 0);
        __syncthreads();   // single barrier per K-step (drains prefetch vmcnt)
        cur ^= 1;
    }

    const int orow = m0 + wr * 32, ocol = n0 + wc * (TN / 2);
#pragma unroll
    for (int mi = 0; mi < 2; mi++)
#pragma unroll
        for (int ni = 0; ni < NB; ni++)
#pragma unroll
            for (int j2 = 0; j2 < 4; j2++) {
                int r = orow + mi * 16 + lb * 4 + j2;
                int c = ocol + ni * 16 + la;
                float v = acc[mi][ni][j2];
                if (EPI == 0) {
                    ((u16*)outp)[(size_t)r * N + c] = f2bf(v);
                } else if (EPI == 1) {
                    ((float*)outp)[(size_t)r * N + c] = v + bias[c] + res[(size_t)r * N + c];
                } else {
                    v += bias[c];
                    ((u16*)outp)[(size_t)r * N + c] = f2bf(fmaxf(v, 0.f));
                }
            }
}

// ---------------- MFMA flash attention (causal), balanced pair scheme ----------------
// QKV: [MROWS][3072] bf16 (Q|K|V each 1024). O: [MROWS][1024] bf16.
// 256 blocks x 512 threads. Block = (b,h) x q-tile PAIR (qt, 15-qt), q-tile = 128 rows.
// 8 waves, each owns 16 q-rows. KV tiles of 64 keys; every block does exactly 34 tile-steps.
#define LDK 72   /* padded LDS row stride (bf16) */
__global__ __launch_bounds__(512) void fattn(const u16* __restrict__ QKV, u16* __restrict__ O) {
    const int t = threadIdx.x, w = t >> 6, lane = t & 63;
    const int la = lane & 15, lb = lane >> 4;
    // decode: xcd = id&7; all 8 pair-blocks of a bh share an XCD (K+V 512KB/bh, 4 bh/XCD -> 2MB in L2)
    const u32 id = blockIdx.x;          // 0..255
    const int bh = (int)((id & 7) * 4 + ((id >> 6) & 3));
    const int p = (int)((id >> 3) & 7); // pair index 0..7
    const int b = bh >> 4, h = bh & 15;

    __shared__ u16 K_lds[64 * LDK];
    __shared__ u16 Vt_lds[64 * LDK];
    __shared__ u16 P_lds[8][16 * LDK];

    const u16* base = QKV + (size_t)(b * SEQ) * 3072 + h * HDIM;
    const u16* Qg = base;
    const u16* Kg = base + 1024;
    const u16* Vg = base + 2048;
    u16* pw = &P_lds[w][0];

    // staging work split: K by all 512 threads (1 x s8v), V-transpose by threads 0..255 (2 x s8v)
    const int krow = t >> 3, kseg = t & 7;
    const int vss = (t >> 5) & 7, vkp = t & 31;
    const bool vstager = (t < 256);

#pragma unroll
    for (int phase = 0; phase < 2; phase++) {
        const int qt = phase ? (15 - p) : p;
        const int qbase = qt * 128;
        const int nkv = 2 * qt + 2;
        const int wq0 = qbase + w * 16;   // wave's first absolute q row

        // Q fragments for this phase
        s8v aq0, aq1;
        {
            const u16* qr = Qg + (size_t)(wq0 + la) * 3072 + lb * 8;
            aq0 = *(const s8v*)(qr);
            aq1 = *(const s8v*)(qr + 32);
        }
        float m[4], l[4];
#pragma unroll
        for (int j = 0; j < 4; j++) { m[j] = -1e30f; l[j] = 0.f; }
        f4v oacc[4] = {};

        // prologue: prefetch tile 0 into registers
        s8v kstg, vstgA, vstgB;
        kstg = *(const s8v*)(Kg + (size_t)krow * 3072 + kseg * 8);
        if (vstager) {
            const u16* v0 = Vg + (size_t)(vkp * 2) * 3072 + vss * 8;
            vstgA = *(const s8v*)(v0);
            vstgB = *(const s8v*)(v0 + 3072);
        }

        for (int kt = 0; kt < nkv; ++kt) {
            const int kv0 = kt * 64;
            // write staged regs -> LDS (vmcnt wait auto-inserted on reg use)
            *(s8v*)&K_lds[krow * LDK + kseg * 8] = kstg;
            if (vstager) {
                u32* vt32 = (u32*)Vt_lds;
#pragma unroll
                for (int j2 = 0; j2 < 8; j2++)
                    vt32[(vss * 8 + j2) * (LDK / 2) + vkp] =
                        (u32)(u16)vstgA[j2] | ((u32)(u16)vstgB[j2] << 16);
            }
            // async prefetch of next tile (in flight across the compute phase)
            if (kt + 1 < nkv) {
                const int nv0 = kv0 + 64;
                kstg = *(const s8v*)(Kg + (size_t)(nv0 + krow) * 3072 + kseg * 8);
                if (vstager) {
                    const u16* v0 = Vg + (size_t)(nv0 + vkp * 2) * 3072 + vss * 8;
                    vstgA = *(const s8v*)(v0);
                    vstgB = *(const s8v*)(v0 + 3072);
                }
            }
            __syncthreads();

            if (kv0 <= wq0 + 15) {   // wave has at least one unmasked key in this tile
                // ---- QK^T ----
                f4v sacc[4] = {};
#pragma unroll
                for (int kc = 0; kc < 4; kc++) {
                    s8v bk0 = *(const s8v*)&K_lds[(kc * 16 + la) * LDK + lb * 8];
                    s8v bk1 = *(const s8v*)&K_lds[(kc * 16 + la) * LDK + 32 + lb * 8];
                    sacc[kc] = __builtin_amdgcn_mfma_f32_16x16x32_bf16(aq0, bk0, sacc[kc], 0, 0, 0);
                    sacc[kc] = __builtin_amdgcn_mfma_f32_16x16x32_bf16(aq1, bk1, sacc[kc], 0, 0, 0);
                }

                // ---- online softmax (rows lb*4+j lane-local) ----
                const bool doMask = (kv0 + 63 > wq0);
#pragma unroll
                for (int j = 0; j < 4; j++) {
                    const int row = wq0 + lb * 4 + j;
                    float s0 = sacc[0][j] * 0.125f;
                    float s1 = sacc[1][j] * 0.125f;
                    float s2 = sacc[2][j] * 0.125f;
                    float s3 = sacc[3][j] * 0.125f;
                    if (doMask) {
                        if (kv0 + 0 * 16 + la > row) s0 = -1e30f;
                        if (kv0 + 1 * 16 + la > row) s1 = -1e30f;
                        if (kv0 + 2 * 16 + la > row) s2 = -1e30f;
                        if (kv0 + 3 * 16 + la > row) s3 = -1e30f;
                    }
                    float mx = fmaxf(fmaxf(s0, s1), fmaxf(s2, s3));
                    mx = fmaxf(mx, __shfl_xor(mx, 1));
                    mx = fmaxf(mx, __shfl_xor(mx, 2));
                    mx = fmaxf(mx, __shfl_xor(mx, 4));
                    mx = fmaxf(mx, __shfl_xor(mx, 8));
                    float mn = fmaxf(m[j], mx);
                    float sc = __expf(m[j] - mn);
                    m[j] = mn;
                    float e0 = __expf(s0 - mn), e1 = __expf(s1 - mn);
                    float e2 = __expf(s2 - mn), e3 = __expf(s3 - mn);
                    float rs = (e0 + e1) + (e2 + e3);
                    rs += __shfl_xor(rs, 1);
                    rs += __shfl_xor(rs, 2);
                    rs += __shfl_xor(rs, 4);
                    rs += __shfl_xor(rs, 8);
                    l[j] = l[j] * sc + rs;
#pragma unroll
                    for (int dt = 0; dt < 4; dt++) oacc[dt][j] *= sc;
                    u16* pr = pw + (lb * 4 + j) * LDK + la;
                    pr[0]  = f2bf(e0);
                    pr[16] = f2bf(e1);
                    pr[32] = f2bf(e2);
                    pr[48] = f2bf(e3);
                }

                // ---- PV: O += P @ V ----
                s8v ap0 = *(const s8v*)&pw[la * LDK + lb * 8];
                s8v ap1 = *(const s8v*)&pw[la * LDK + 32 + lb * 8];
#pragma unroll
                for (int dt = 0; dt < 4; dt++) {
                    s8v v0 = *(const s8v*)&Vt_lds[(dt * 16 + la) * LDK + lb * 8];
                    s8v v1 = *(const s8v*)&Vt_lds[(dt * 16 + la) * LDK + 32 + lb * 8];
                    oacc[dt] = __builtin_amdgcn_mfma_f32_16x16x32_bf16(ap0, v0, oacc[dt], 0, 0, 0);
                    oacc[dt] = __builtin_amdgcn_mfma_f32_16x16x32_bf16(ap1, v1, oacc[dt], 0, 0, 0);
                }
            }
            __syncthreads();
        }

        // ---- epilogue for this phase ----
#pragma unroll
        for (int dt = 0; dt < 4; dt++) {
#pragma unroll
            for (int j = 0; j < 4; j++) {
                const int q = wq0 + lb * 4 + j;
                O[(size_t)(b * SEQ + q) * EMB + h * HDIM + dt * 16 + la] = f2bf(oacc[dt][j] / l[j]);
            }
        }
    }
}

extern "C" void kernel_launch(void* const* d_in, const int* in_sizes, int n_in,
                              void* d_out, int out_size, void* d_ws, size_t ws_size,
                              hipStream_t stream) {
    const float* x    = (const float*)d_in[0];
    const float* Wq   = (const float*)d_in[1];
    const float* Wk   = (const float*)d_in[2];
    const float* Wv   = (const float*)d_in[3];
    const float* Wo   = (const float*)d_in[4];
    const float* bo   = (const float*)d_in[5];
    const float* ln1w = (const float*)d_in[6];
    const float* ln1b = (const float*)d_in[7];
    const float* ln2w = (const float*)d_in[8];
    const float* ln2b = (const float*)d_in[9];
    const float* W1   = (const float*)d_in[10];
    const float* b1   = (const float*)d_in[11];
    const float* W2   = (const float*)d_in[12];
    const float* b2   = (const float*)d_in[13];

    // ---- workspace layout: exactly 64MB ----
    const size_t MB = 1024 * 1024;
    char* ws = (char*)d_ws;
    u16* WqkvT = (u16*)(ws);              // [3072][1024] bf16 = 6MB
    u16* WoT   = (u16*)(ws + 6 * MB);     // [1024][1024] = 2MB
    u16* W1T   = (u16*)(ws + 8 * MB);     // [4096][1024] = 8MB
    u16* W2T   = (u16*)(ws + 16 * MB);    // [1024][4096] = 8MB
    u16* xn    = (u16*)(ws + 24 * MB);    // [4096][1024] = 8MB
    u16* QKV   = (u16*)(ws + 32 * MB);    // [4096][3072] = 24MB
    u16* mid   = (u16*)(ws + 32 * MB);    // [4096][4096] = 32MB (reuses QKV region)
    u16* hn    = xn;                      // LN2 out reuses xn (dead after h-GEMM)
    float* hbuf = (float*)d_out;          // h lives in d_out (f32)

    dim3 tb(32, 8);
    transpose_cast<<<dim3(32, 32), tb, 0, stream>>>(Wq, WqkvT, 1024, 1024);
    transpose_cast<<<dim3(32, 32), tb, 0, stream>>>(Wk, WqkvT + (size_t)1024 * 1024, 1024, 1024);
    transpose_cast<<<dim3(32, 32), tb, 0, stream>>>(Wv, WqkvT + (size_t)2048 * 1024, 1024, 1024);
    transpose_cast<<<dim3(32, 32), tb, 0, stream>>>(Wo, WoT, 1024, 1024);
    transpose_cast<<<dim3(128, 32), tb, 0, stream>>>(W1, W1T, 1024, 4096);
    transpose_cast<<<dim3(32, 128), tb, 0, stream>>>(W2, W2T, 4096, 1024);

    ln_kernel<<<MROWS, 256, 0, stream>>>(x, ln1w, ln1b, xn);

    // QKV: [4096][3072]   grid = (N/128)*64 = 1536 blocks (6/CU)
    gemm_bt<0, 128><<<dim3((3072 / 128) * 64), 256, 0, stream>>>(
        xn, WqkvT, nullptr, nullptr, QKV, MROWS, 3072, 1024);

    // flash attention -> xn (reuse; QKV fully consumed here)
    fattn<<<dim3(256), 512, 0, stream>>>(QKV, xn);

    // h = x + attn @ Wo + bo  -> d_out (f32)   grid = (1024/64)*64 = 1024 blocks (4/CU)
    gemm_bt<1, 64><<<dim3((1024 / 64) * 64), 256, 0, stream>>>(
        xn, WoT, bo, x, hbuf, MROWS, 1024, 1024);

    // hn = LN2(h) (xn region is dead now)
    ln_kernel<<<MROWS, 256, 0, stream>>>(hbuf, ln2w, ln2b, hn);

    // mid = relu(hn @ W1 + b1)   grid = (4096/128)*64 = 2048 blocks (8/CU)
    gemm_bt<2, 128><<<dim3((HID / 128) * 64), 256, 0, stream>>>(
        hn, W1T, b1, nullptr, mid, MROWS, HID, 1024);

    // out = h + mid @ W2 + b2  (in-place on d_out)   grid = 1024 blocks (4/CU)
    gemm_bt<1, 64><<<dim3((1024 / 64) * 64), 256, 0, stream>>>(
        mid, W2T, b2, hbuf, hbuf, MROWS, 1024, HID);
}